// Round 1
// 3128.073 us; speedup vs baseline: 1.0312x; 1.0312x over previous
//
#include <hip/hip_runtime.h>
#include <stdint.h>
#include <stddef.h>

// MLP: out0 = X@Win + b_in ; out1 = relu(out0@W1 + b1) ; out2 = relu(out1@W2 + b2)
// B=4096, D_IN=32000, H0=H1=4000, TAIL=2000. All inputs fp32, output fp32.
// Strategy: bf16 MFMA (16x16x32), fp32 accumulate. 128x128x32 tiles, 4 waves/block.
// This revision (R1): global_load_lds width-16 direct staging (m97 structure),
// XOR-swizzled LDS (linear dest + pre-swizzled global src + swizzled read),
// bijective XCD blockIdx swizzle.

typedef __attribute__((ext_vector_type(8))) short short8;
typedef __attribute__((ext_vector_type(4))) float f32x4;
typedef __attribute__((ext_vector_type(4))) uint32_t u32x4;
typedef __attribute__((ext_vector_type(2))) uint32_t u32x2;

__device__ __forceinline__ uint32_t f2bf_bits(float f) {
  uint32_t u = __builtin_bit_cast(uint32_t, f);
  u += 0x7FFFu + ((u >> 16) & 1u);   // round-to-nearest-even
  return u >> 16;
}
__device__ __forceinline__ uint32_t pk2(float a, float b) {
  return f2bf_bits(a) | (f2bf_bits(b) << 16);
}

// global -> LDS direct DMA, 16 bytes per lane. LDS dest = wave-uniform base + lane*16.
__device__ __forceinline__ void gload_lds16(const uint16_t* g, uint16_t* l) {
  __builtin_amdgcn_global_load_lds(
      (const __attribute__((address_space(1))) uint32_t*)g,
      (__attribute__((address_space(3))) uint32_t*)l, 16, 0, 0);
}

// ---- bulk fp32 -> bf16 convert (8 elems/thread). n divisible by 8. ----
__global__ __launch_bounds__(256)
void cvt_bf16_kernel(const float* __restrict__ in, uint32_t* __restrict__ out, size_t n) {
  size_t i = ((size_t)blockIdx.x * 256 + threadIdx.x) * 8;
  if (i + 8 <= n) {
    f32x4 a = *(const f32x4*)(in + i);
    f32x4 b = *(const f32x4*)(in + i + 4);
    u32x4 o = {pk2(a.x, a.y), pk2(a.z, a.w), pk2(b.x, b.y), pk2(b.z, b.w)};
    *(u32x4*)(out + i / 2) = o;
  }
}

// ---- transpose + convert: in fp32 [K][N] -> out bf16 [N][K]. K % 32 == 0. ----
__global__ __launch_bounds__(256)
void cvtT_bf16_kernel(const float* __restrict__ in, uint16_t* __restrict__ out, int K, int N) {
  __shared__ float tile[32][33];
  const int kb = blockIdx.y * 32;
  const int nb = blockIdx.x * 32;
  const int tx = threadIdx.x & 31;
  const int ty = threadIdx.x >> 5;   // 0..7
  const int ncol = nb + tx;
#pragma unroll
  for (int i = 0; i < 32; i += 8)
    tile[ty + i][tx] = (ncol < N) ? in[(size_t)(kb + ty + i) * N + ncol] : 0.f;
  __syncthreads();
#pragma unroll
  for (int i = 0; i < 32; i += 8) {
    int nrow = nb + ty + i;
    if (nrow < N)
      out[(size_t)nrow * K + (kb + tx)] = (uint16_t)f2bf_bits(tile[tx][ty + i]);
  }
}

// ============================================================================
// Fast GEMM: C[M][N] = act(A[M][K] @ Bt[N][K]^T + bias), A and Bt already bf16.
// M % 128 == 0, K % 32 == 0; N may be partial in last x-block.
// m97 structure: global_load_lds(16B) -> linear LDS [128][32] -> ds_read_b128.
// XOR swizzle: 16B slot s is stored at physical slot s ^ ((row>>1)&3).
//   - staging pre-swizzles the GLOBAL source column (gload_lds dest is linear)
//   - fragment reads apply the same XOR; per-thread it folds to a constant.
// ============================================================================
template<bool RELU, bool OBF16>
__global__ __launch_bounds__(256, 2)
void mlp_gemm_fast(const uint16_t* __restrict__ A, const uint16_t* __restrict__ Bt,
                   const float* __restrict__ bias, void* __restrict__ Cp,
                   int M, int N, int K)
{
  __shared__ uint16_t As[128 * 32];   // 8 KB, linear [row][32]
  __shared__ uint16_t Bs[128 * 32];   // 8 KB, linear [row][32] (rows = B columns)

  const int tid  = threadIdx.x;
  const int lane = tid & 63;
  const int wave = __builtin_amdgcn_readfirstlane(tid >> 6);

  // ---- bijective XCD swizzle of flattened block index (nwg % 8 == 0 here) ----
  const int gx = gridDim.x;
  int nwg = gx * (int)gridDim.y;
  int wg = (int)blockIdx.y * gx + (int)blockIdx.x;
  if ((nwg & 7) == 0) { int c = nwg >> 3; wg = (wg & 7) * c + (wg >> 3); }
  const int n0 = (wg % gx) << 7;
  const int m0 = (wg / gx) << 7;

  const int wm = (wave & 1) << 6;
  const int wn = (wave >> 1) << 6;
  const int fl = lane & 15;    // MFMA: A row / B col / C col
  const int kg = lane >> 4;    // k-group 0..3

  // ---- staging geometry: each wave issues 2 gload_lds per matrix per iter ----
  const int sr = lane >> 2;              // row within 16-row group (0..15)
  const int sp = lane & 3;               // physical 16B slot this lane fills
  const int r0 = wave * 32 + sr;         // tile row for instr 0; instr 1 = r0+16
  // logical slot that must land at physical slot sp of row r0 (same for r0+16,
  // since +16 doesn't change (row>>1)&3):
  const int ssw = ((sp ^ ((r0 >> 1) & 3)) << 3);   // element offset 0/8/16/24

  const uint16_t* gA0 = A + (size_t)(m0 + r0) * K + ssw;
  const uint16_t* gA1 = gA0 + (size_t)16 * K;
  int bn0 = n0 + r0;      if (bn0 > N - 1) bn0 = N - 1;   // clamp OOB B^T rows
  int bn1 = n0 + r0 + 16; if (bn1 > N - 1) bn1 = N - 1;
  const uint16_t* gB0 = Bt + (size_t)bn0 * K + ssw;
  const uint16_t* gB1 = Bt + (size_t)bn1 * K + ssw;

  uint16_t* lA0 = &As[wave * 1024];      // wave's 32 rows, first 16
  uint16_t* lA1 = lA0 + 512;             // next 16 rows
  uint16_t* lB0 = &Bs[wave * 1024];
  uint16_t* lB1 = lB0 + 512;

  // ---- fragment-read column: XOR swizzle folds to a per-thread constant ----
  // row = wm + t*16 + fl  =>  (row>>1)&3 == (fl>>1)&3  (wm, 16t drop out)
  const int colsw = ((kg ^ ((fl >> 1) & 3)) << 3);

  f32x4 acc[4][4];
#pragma unroll
  for (int i = 0; i < 4; ++i)
#pragma unroll
    for (int j = 0; j < 4; ++j)
      acc[i][j] = f32x4{0.f, 0.f, 0.f, 0.f};

  for (int k0 = 0; k0 < K; k0 += 32) {
    gload_lds16(gA0, lA0);
    gload_lds16(gA1, lA1);
    gload_lds16(gB0, lB0);
    gload_lds16(gB1, lB1);
    gA0 += 32; gA1 += 32; gB0 += 32; gB1 += 32;
    __syncthreads();   // drains vmcnt(0): staged data visible

    short8 af[4], bfr[4];
#pragma unroll
    for (int t = 0; t < 4; ++t) {
      af[t]  = *(const short8*)&As[(wm + t * 16 + fl) * 32 + colsw];
      bfr[t] = *(const short8*)&Bs[(wn + t * 16 + fl) * 32 + colsw];
    }
#pragma unroll
    for (int tm = 0; tm < 4; ++tm)
#pragma unroll
      for (int tn = 0; tn < 4; ++tn)
        acc[tm][tn] = __builtin_amdgcn_mfma_f32_16x16x32_bf16(af[tm], bfr[tn], acc[tm][tn], 0, 0, 0);
    __syncthreads();   // protect LDS before next iter's DMA overwrites it
  }

  // ---- epilogue: bias (+relu), store. C/D layout: col=lane&15, row=kg*4+reg ----
#pragma unroll
  for (int tn = 0; tn < 4; ++tn) {
    int n = n0 + wn + tn * 16 + fl;
    if (n < N) {
      float bv = bias[n];
#pragma unroll
      for (int tm = 0; tm < 4; ++tm) {
        size_t base = (size_t)(m0 + wm + tm * 16 + kg * 4) * N + n;
#pragma unroll
        for (int r = 0; r < 4; ++r) {
          float v = acc[tm][tn][r] + bv;
          if constexpr (RELU) v = fmaxf(v, 0.f);
          if constexpr (OBF16)
            ((uint16_t*)Cp)[base + (size_t)r * N] = (uint16_t)f2bf_bits(v);
          else
            ((float*)Cp)[base + (size_t)r * N] = v;
        }
      }
    }
  }
}

// ============================================================================
// Fallback GEMM (slow path only): inline conversion/transpose in staging.
// ============================================================================
template<bool ABF16, bool BTBF16, bool RELU, bool OBF16>
__global__ __launch_bounds__(256, 2)
void mlp_gemm(const void* __restrict__ Ap, const void* __restrict__ Bp,
              const float* __restrict__ bias, void* __restrict__ Cp,
              int M, int N, int K)
{
  __shared__ uint16_t As[128][40];
  __shared__ uint16_t Bs[128][40];   // [n][k]

  const int tid  = threadIdx.x;
  const int lane = tid & 63;
  const int wave = tid >> 6;
  const int wm = (wave & 1) << 6;
  const int wn = (wave >> 1) << 6;
  const int fl = lane & 15;
  const int kg = lane >> 4;

  const int m0 = blockIdx.y << 7;
  const int n0 = blockIdx.x << 7;

  const int ar = tid >> 1;
  const int ah = (tid & 1) << 4;
  const int bkb = tid >> 5;
  const int bnb = tid & 31;

  const bool n_full = (n0 + 128 <= N);
  const int brow = (n0 + ar < N) ? (n0 + ar) : (N - 1);

  f32x4 acc[4][4];
#pragma unroll
  for (int i = 0; i < 4; ++i)
#pragma unroll
    for (int j = 0; j < 4; ++j)
      acc[i][j] = f32x4{0.f, 0.f, 0.f, 0.f};

  for (int k0 = 0; k0 < K; k0 += 32) {
    {
      u32x4 w0, w1;
      if constexpr (ABF16) {
        const uint16_t* A = (const uint16_t*)Ap;
        const uint16_t* p = A + (size_t)(m0 + ar) * K + (k0 + ah);
        w0 = ((const u32x4*)p)[0];
        w1 = ((const u32x4*)p)[1];
      } else {
        const float* A = (const float*)Ap;
        const float* p = A + (size_t)(m0 + ar) * K + (k0 + ah);
        f32x4 a0 = ((const f32x4*)p)[0];
        f32x4 a1 = ((const f32x4*)p)[1];
        f32x4 a2 = ((const f32x4*)p)[2];
        f32x4 a3 = ((const f32x4*)p)[3];
        w0 = u32x4{pk2(a0.x, a0.y), pk2(a0.z, a0.w), pk2(a1.x, a1.y), pk2(a1.z, a1.w)};
        w1 = u32x4{pk2(a2.x, a2.y), pk2(a2.z, a2.w), pk2(a3.x, a3.y), pk2(a3.z, a3.w)};
      }
      u32x4* d = (u32x4*)&As[ar][ah];
      d[0] = w0; d[1] = w1;
    }
    if constexpr (BTBF16) {
      const uint16_t* Bt = (const uint16_t*)Bp;
      const uint16_t* p = Bt + (size_t)brow * K + (k0 + ah);
      u32x4 w0 = ((const u32x4*)p)[0];
      u32x4 w1 = ((const u32x4*)p)[1];
      u32x4* d = (u32x4*)&Bs[ar][ah];
      d[0] = w0; d[1] = w1;
    } else {
      const float* Bmat = (const float*)Bp;
      if (n_full) {
        const float* p = Bmat + (size_t)(k0 + bkb * 4) * N + (n0 + bnb * 4);
        f32x4 r0 = *(const f32x4*)p;
        f32x4 r1 = *(const f32x4*)(p + (size_t)N);
        f32x4 r2 = *(const f32x4*)(p + 2 * (size_t)N);
        f32x4 r3 = *(const f32x4*)(p + 3 * (size_t)N);
#pragma unroll
        for (int ii = 0; ii < 4; ++ii) {
          u32x2 w = {pk2(r0[ii], r1[ii]), pk2(r2[ii], r3[ii])};
          *(u32x2*)&Bs[bnb * 4 + ii][bkb * 4] = w;
        }
      } else {
#pragma unroll
        for (int ii = 0; ii < 4; ++ii) {
          int n = n0 + bnb * 4 + ii;
          uint32_t b0 = 0, b1 = 0, b2 = 0, b3 = 0;
          if (n < N) {
            size_t o = (size_t)(k0 + bkb * 4) * N + n;
            b0 = f2bf_bits(Bmat[o]);
            b1 = f2bf_bits(Bmat[o + (size_t)N]);
            b2 = f2bf_bits(Bmat[o + 2 * (size_t)N]);
            b3 = f2bf_bits(Bmat[o + 3 * (size_t)N]);
          }
          u32x2 w = {b0 | (b1 << 16), b2 | (b3 << 16)};
          *(u32x2*)&Bs[bnb * 4 + ii][bkb * 4] = w;
        }
      }
    }
    __syncthreads();

    short8 af[4], bfr[4];
#pragma unroll
    for (int t = 0; t < 4; ++t) {
      af[t]  = *(const short8*)&As[wm + t * 16 + fl][kg * 8];
      bfr[t] = *(const short8*)&Bs[wn + t * 16 + fl][kg * 8];
    }
#pragma unroll
    for (int tm = 0; tm < 4; ++tm)
#pragma unroll
      for (int tn = 0; tn < 4; ++tn)
        acc[tm][tn] = __builtin_amdgcn_mfma_f32_16x16x32_bf16(af[tm], bfr[tn], acc[tm][tn], 0, 0, 0);
    __syncthreads();
  }

#pragma unroll
  for (int tn = 0; tn < 4; ++tn) {
    int n = n0 + wn + tn * 16 + fl;
    if (n < N) {
      float bv = bias[n];
#pragma unroll
      for (int tm = 0; tm < 4; ++tm) {
        size_t base = (size_t)(m0 + wm + tm * 16 + kg * 4) * N + n;
#pragma unroll
        for (int r = 0; r < 4; ++r) {
          float v = acc[tm][tn][r] + bv;
          if constexpr (RELU) v = fmaxf(v, 0.f);
          if constexpr (OBF16)
            ((uint16_t*)Cp)[base + (size_t)r * N] = (uint16_t)f2bf_bits(v);
          else
            ((float*)Cp)[base + (size_t)r * N] = v;
        }
      }
    }
  }
}

extern "C" void kernel_launch(void* const* d_in, const int* in_sizes, int n_in,
                              void* d_out, int out_size, void* d_ws, size_t ws_size,
                              hipStream_t stream) {
  const float* X   = (const float*)d_in[0];
  const float* Win = (const float*)d_in[1];
  const float* bin = (const float*)d_in[2];
  const float* W1  = (const float*)d_in[3];
  const float* b1  = (const float*)d_in[4];
  const float* W2  = (const float*)d_in[5];
  const float* b2  = (const float*)d_in[6];
  float* out = (float*)d_out;

  const int Bm = 4096, DIN = 32000, H0 = 4000, H1 = 4000, TL = 2000;
  const size_t sX  = (size_t)Bm * DIN;
  const size_t sWi = (size_t)DIN * H0;
  const size_t sW1 = (size_t)H0 * H1;
  const size_t sW2 = (size_t)H1 * TL;
  const size_t st0 = (size_t)Bm * H0;
  const size_t st1 = (size_t)Bm * H1;
  const size_t need_fast = 2 * (sX + sWi + sW1 + sW2 + st0 + st1);  // ~602 MiB

  dim3 blk(256);

  if (ws_size >= need_fast) {
    // fast path: pre-convert X, pre-transpose+convert weights -> bf16
    uint8_t* w = (uint8_t*)d_ws;
    uint16_t* Xb  = (uint16_t*)w; w += 2 * sX;
    uint16_t* WiT = (uint16_t*)w; w += 2 * sWi;
    uint16_t* W1T = (uint16_t*)w; w += 2 * sW1;
    uint16_t* W2T = (uint16_t*)w; w += 2 * sW2;
    uint16_t* t0  = (uint16_t*)w; w += 2 * st0;
    uint16_t* t1  = (uint16_t*)w;

    cvt_bf16_kernel<<<dim3((unsigned)((sX / 8 + 255) / 256)), blk, 0, stream>>>(X, (uint32_t*)Xb, sX);
    cvtT_bf16_kernel<<<dim3((H0 + 31) / 32, DIN / 32), blk, 0, stream>>>(Win, WiT, DIN, H0);
    cvtT_bf16_kernel<<<dim3((H1 + 31) / 32, H0 / 32), blk, 0, stream>>>(W1, W1T, H0, H1);
    cvtT_bf16_kernel<<<dim3((TL + 31) / 32, H1 / 32), blk, 0, stream>>>(W2, W2T, H1, TL);

    mlp_gemm_fast<false, true><<<dim3((H0 + 127) / 128, Bm / 128), blk, 0, stream>>>(
        Xb, WiT, bin, t0, Bm, H0, DIN);
    mlp_gemm_fast<true, true><<<dim3((H1 + 127) / 128, Bm / 128), blk, 0, stream>>>(
        t0, W1T, b1, t1, Bm, H1, H0);
    mlp_gemm_fast<true, false><<<dim3((TL + 127) / 128, Bm / 128), blk, 0, stream>>>(
        t1, W2T, b2, out, Bm, TL, H1);
  } else {
    // slow path: inline conversion/transpose in GEMM staging; ws only for t0/t1
    uint16_t* t0 = (uint16_t*)d_ws;
    uint16_t* t1 = t0 + st0;

    mlp_gemm<false, false, false, true><<<dim3((H0 + 127) / 128, Bm / 128), blk, 0, stream>>>(
        X, Win, bin, t0, Bm, H0, DIN);
    mlp_gemm<true, false, true, true><<<dim3((H1 + 127) / 128, Bm / 128), blk, 0, stream>>>(
        t0, W1, b1, t1, Bm, H1, H0);
    mlp_gemm<true, false, true, false><<<dim3((TL + 127) / 128, Bm / 128), blk, 0, stream>>>(
        t1, W2, b2, out, Bm, TL, H1);
  }
}

// Round 2
// 3117.972 us; speedup vs baseline: 1.0346x; 1.0032x over previous
//
#include <hip/hip_runtime.h>
#include <stdint.h>
#include <stddef.h>

// MLP: out0 = X@Win + b_in ; out1 = relu(out0@W1 + b1) ; out2 = relu(out1@W2 + b2)
// B=4096, D_IN=32000, H0=H1=4000, TAIL=2000. All inputs fp32, output fp32.
// Strategy: bf16 MFMA (16x16x32), fp32 accumulate. 128x128x32 tiles, 4 waves/block.
// R1: global_load_lds(16B) staging, XOR-swizzled LDS, XCD blockIdx swizzle.
// R2: double-buffered LDS + prefetch-next-tile with COUNTED s_waitcnt vmcnt(4)
//     across raw s_barrier (T3/T4): hides HBM latency that the __syncthreads()
//     vmcnt(0) drain was exposing every k-step.

typedef __attribute__((ext_vector_type(8))) short short8;
typedef __attribute__((ext_vector_type(4))) float f32x4;
typedef __attribute__((ext_vector_type(4))) uint32_t u32x4;
typedef __attribute__((ext_vector_type(2))) uint32_t u32x2;

__device__ __forceinline__ uint32_t f2bf_bits(float f) {
  uint32_t u = __builtin_bit_cast(uint32_t, f);
  u += 0x7FFFu + ((u >> 16) & 1u);   // round-to-nearest-even
  return u >> 16;
}
__device__ __forceinline__ uint32_t pk2(float a, float b) {
  return f2bf_bits(a) | (f2bf_bits(b) << 16);
}

// global -> LDS direct DMA, 16 bytes per lane. LDS dest = wave-uniform base + lane*16.
__device__ __forceinline__ void gload_lds16(const uint16_t* g, uint16_t* l) {
  __builtin_amdgcn_global_load_lds(
      (const __attribute__((address_space(1))) uint32_t*)g,
      (__attribute__((address_space(3))) uint32_t*)l, 16, 0, 0);
}

// ---- bulk fp32 -> bf16 convert (8 elems/thread). n divisible by 8. ----
__global__ __launch_bounds__(256)
void cvt_bf16_kernel(const float* __restrict__ in, uint32_t* __restrict__ out, size_t n) {
  size_t i = ((size_t)blockIdx.x * 256 + threadIdx.x) * 8;
  if (i + 8 <= n) {
    f32x4 a = *(const f32x4*)(in + i);
    f32x4 b = *(const f32x4*)(in + i + 4);
    u32x4 o = {pk2(a.x, a.y), pk2(a.z, a.w), pk2(b.x, b.y), pk2(b.z, b.w)};
    *(u32x4*)(out + i / 2) = o;
  }
}

// ---- transpose + convert: in fp32 [K][N] -> out bf16 [N][K]. K % 32 == 0. ----
__global__ __launch_bounds__(256)
void cvtT_bf16_kernel(const float* __restrict__ in, uint16_t* __restrict__ out, int K, int N) {
  __shared__ float tile[32][33];
  const int kb = blockIdx.y * 32;
  const int nb = blockIdx.x * 32;
  const int tx = threadIdx.x & 31;
  const int ty = threadIdx.x >> 5;   // 0..7
  const int ncol = nb + tx;
#pragma unroll
  for (int i = 0; i < 32; i += 8)
    tile[ty + i][tx] = (ncol < N) ? in[(size_t)(kb + ty + i) * N + ncol] : 0.f;
  __syncthreads();
#pragma unroll
  for (int i = 0; i < 32; i += 8) {
    int nrow = nb + ty + i;
    if (nrow < N)
      out[(size_t)nrow * K + (kb + tx)] = (uint16_t)f2bf_bits(tile[tx][ty + i]);
  }
}

// ============================================================================
// Fast GEMM: C[M][N] = act(A[M][K] @ Bt[N][K]^T + bias), A and Bt already bf16.
// M % 128 == 0, K % 32 == 0; N may be partial in last x-block.
// Double-buffered m97 structure: prefetch tile t+1 via global_load_lds while
// computing tile t; counted vmcnt(4) keeps next-tile DMA in flight across the
// barrier. XOR swizzle: 16B slot s stored at physical slot s ^ ((row>>1)&3);
// staging pre-swizzles the GLOBAL source column (gload_lds dest stays linear),
// fragment reads apply the same XOR (folds to a per-thread constant).
// ============================================================================
template<bool RELU, bool OBF16>
__global__ __launch_bounds__(256, 2)
void mlp_gemm_fast(const uint16_t* __restrict__ A, const uint16_t* __restrict__ Bt,
                   const float* __restrict__ bias, void* __restrict__ Cp,
                   int M, int N, int K)
{
  __shared__ uint16_t As[2][128 * 32];   // 2 x 8 KB, linear [row][32]
  __shared__ uint16_t Bs[2][128 * 32];   // rows = B columns

  const int tid  = threadIdx.x;
  const int lane = tid & 63;
  const int wave = __builtin_amdgcn_readfirstlane(tid >> 6);

  // ---- bijective XCD swizzle of flattened block index (nwg % 8 == 0 here) ----
  const int gx = gridDim.x;
  int nwg = gx * (int)gridDim.y;
  int wg = (int)blockIdx.y * gx + (int)blockIdx.x;
  if ((nwg & 7) == 0) { int c = nwg >> 3; wg = (wg & 7) * c + (wg >> 3); }
  const int n0 = (wg % gx) << 7;
  const int m0 = (wg / gx) << 7;

  const int wm = (wave & 1) << 6;
  const int wn = (wave >> 1) << 6;
  const int fl = lane & 15;    // MFMA: A row / B col / C col
  const int kg = lane >> 4;    // k-group 0..3

  // ---- staging geometry: each wave issues 2 gload_lds per matrix per tile ----
  const int sr = lane >> 2;              // row within 16-row group (0..15)
  const int sp = lane & 3;               // physical 16B slot this lane fills
  const int r0 = wave * 32 + sr;         // tile row for instr 0; instr 1 = r0+16
  // logical slot that must land at physical slot sp of row r0 (same for r0+16):
  const int ssw = ((sp ^ ((r0 >> 1) & 3)) << 3);   // element offset 0/8/16/24

  const uint16_t* gA0 = A + (size_t)(m0 + r0) * K + ssw;
  const uint16_t* gA1 = gA0 + (size_t)16 * K;
  int bn0 = n0 + r0;      if (bn0 > N - 1) bn0 = N - 1;   // clamp OOB B^T rows
  int bn1 = n0 + r0 + 16; if (bn1 > N - 1) bn1 = N - 1;
  const uint16_t* gB0 = Bt + (size_t)bn0 * K + ssw;
  const uint16_t* gB1 = Bt + (size_t)bn1 * K + ssw;

  const int lofs = wave * 1024;          // this wave's 32-row region (elements)

  // ---- fragment-read column: XOR swizzle folds to a per-thread constant ----
  const int colsw = ((kg ^ ((fl >> 1) & 3)) << 3);

  f32x4 acc[4][4];
#pragma unroll
  for (int i = 0; i < 4; ++i)
#pragma unroll
    for (int j = 0; j < 4; ++j)
      acc[i][j] = f32x4{0.f, 0.f, 0.f, 0.f};

  // stage one 128x32 A-tile + B-tile into buffer `buf`, advance global ptrs
  auto stage = [&](int buf) {
    uint16_t* a = &As[buf][lofs];
    uint16_t* b = &Bs[buf][lofs];
    gload_lds16(gA0, a);
    gload_lds16(gA1, a + 512);
    gload_lds16(gB0, b);
    gload_lds16(gB1, b + 512);
    gA0 += 32; gA1 += 32; gB0 += 32; gB1 += 32;
  };

  const int nt = K >> 5;
  stage(0);                              // prologue: tile 0 in flight (vmcnt=4)

  for (int t = 0; t < nt; ++t) {
    const int cur = t & 1;
    if (t + 1 < nt) {
      stage(cur ^ 1);                    // issue next tile (vmcnt -> 8)
      asm volatile("s_waitcnt vmcnt(4)" ::: "memory");   // cur's 4 complete
    } else {
      asm volatile("s_waitcnt vmcnt(0)" ::: "memory");   // drain last tile
    }
    __builtin_amdgcn_s_barrier();        // all waves: cur buffer ready
    __builtin_amdgcn_sched_barrier(0);   // no LDS reads above the barrier

    const uint16_t* Asr = As[cur];
    const uint16_t* Bsr = Bs[cur];
    short8 af[4], bfr[4];
#pragma unroll
    for (int q = 0; q < 4; ++q) {
      af[q]  = *(const short8*)&Asr[(wm + q * 16 + fl) * 32 + colsw];
      bfr[q] = *(const short8*)&Bsr[(wn + q * 16 + fl) * 32 + colsw];
    }
#pragma unroll
    for (int tm = 0; tm < 4; ++tm)
#pragma unroll
      for (int tn = 0; tn < 4; ++tn)
        acc[tm][tn] = __builtin_amdgcn_mfma_f32_16x16x32_bf16(af[tm], bfr[tn], acc[tm][tn], 0, 0, 0);

    __builtin_amdgcn_sched_barrier(0);   // no LDS reads below the barrier
    __builtin_amdgcn_s_barrier();        // all reads of cur done before overwrite
  }

  // ---- epilogue: bias (+relu), store. C/D layout: col=lane&15, row=kg*4+reg ----
#pragma unroll
  for (int tn = 0; tn < 4; ++tn) {
    int n = n0 + wn + tn * 16 + fl;
    if (n < N) {
      float bv = bias[n];
#pragma unroll
      for (int tm = 0; tm < 4; ++tm) {
        size_t base = (size_t)(m0 + wm + tm * 16 + kg * 4) * N + n;
#pragma unroll
        for (int r = 0; r < 4; ++r) {
          float v = acc[tm][tn][r] + bv;
          if constexpr (RELU) v = fmaxf(v, 0.f);
          if constexpr (OBF16)
            ((uint16_t*)Cp)[base + (size_t)r * N] = (uint16_t)f2bf_bits(v);
          else
            ((float*)Cp)[base + (size_t)r * N] = v;
        }
      }
    }
  }
}

// ============================================================================
// Fallback GEMM (slow path only): inline conversion/transpose in staging.
// ============================================================================
template<bool ABF16, bool BTBF16, bool RELU, bool OBF16>
__global__ __launch_bounds__(256, 2)
void mlp_gemm(const void* __restrict__ Ap, const void* __restrict__ Bp,
              const float* __restrict__ bias, void* __restrict__ Cp,
              int M, int N, int K)
{
  __shared__ uint16_t As[128][40];
  __shared__ uint16_t Bs[128][40];   // [n][k]

  const int tid  = threadIdx.x;
  const int lane = tid & 63;
  const int wave = tid >> 6;
  const int wm = (wave & 1) << 6;
  const int wn = (wave >> 1) << 6;
  const int fl = lane & 15;
  const int kg = lane >> 4;

  const int m0 = blockIdx.y << 7;
  const int n0 = blockIdx.x << 7;

  const int ar = tid >> 1;
  const int ah = (tid & 1) << 4;
  const int bkb = tid >> 5;
  const int bnb = tid & 31;

  const bool n_full = (n0 + 128 <= N);
  const int brow = (n0 + ar < N) ? (n0 + ar) : (N - 1);

  f32x4 acc[4][4];
#pragma unroll
  for (int i = 0; i < 4; ++i)
#pragma unroll
    for (int j = 0; j < 4; ++j)
      acc[i][j] = f32x4{0.f, 0.f, 0.f, 0.f};

  for (int k0 = 0; k0 < K; k0 += 32) {
    {
      u32x4 w0, w1;
      if constexpr (ABF16) {
        const uint16_t* A = (const uint16_t*)Ap;
        const uint16_t* p = A + (size_t)(m0 + ar) * K + (k0 + ah);
        w0 = ((const u32x4*)p)[0];
        w1 = ((const u32x4*)p)[1];
      } else {
        const float* A = (const float*)Ap;
        const float* p = A + (size_t)(m0 + ar) * K + (k0 + ah);
        f32x4 a0 = ((const f32x4*)p)[0];
        f32x4 a1 = ((const f32x4*)p)[1];
        f32x4 a2 = ((const f32x4*)p)[2];
        f32x4 a3 = ((const f32x4*)p)[3];
        w0 = u32x4{pk2(a0.x, a0.y), pk2(a0.z, a0.w), pk2(a1.x, a1.y), pk2(a1.z, a1.w)};
        w1 = u32x4{pk2(a2.x, a2.y), pk2(a2.z, a2.w), pk2(a3.x, a3.y), pk2(a3.z, a3.w)};
      }
      u32x4* d = (u32x4*)&As[ar][ah];
      d[0] = w0; d[1] = w1;
    }
    if constexpr (BTBF16) {
      const uint16_t* Bt = (const uint16_t*)Bp;
      const uint16_t* p = Bt + (size_t)brow * K + (k0 + ah);
      u32x4 w0 = ((const u32x4*)p)[0];
      u32x4 w1 = ((const u32x4*)p)[1];
      u32x4* d = (u32x4*)&Bs[ar][ah];
      d[0] = w0; d[1] = w1;
    } else {
      const float* Bmat = (const float*)Bp;
      if (n_full) {
        const float* p = Bmat + (size_t)(k0 + bkb * 4) * N + (n0 + bnb * 4);
        f32x4 r0 = *(const f32x4*)p;
        f32x4 r1 = *(const f32x4*)(p + (size_t)N);
        f32x4 r2 = *(const f32x4*)(p + 2 * (size_t)N);
        f32x4 r3 = *(const f32x4*)(p + 3 * (size_t)N);
#pragma unroll
        for (int ii = 0; ii < 4; ++ii) {
          u32x2 w = {pk2(r0[ii], r1[ii]), pk2(r2[ii], r3[ii])};
          *(u32x2*)&Bs[bnb * 4 + ii][bkb * 4] = w;
        }
      } else {
#pragma unroll
        for (int ii = 0; ii < 4; ++ii) {
          int n = n0 + bnb * 4 + ii;
          uint32_t b0 = 0, b1 = 0, b2 = 0, b3 = 0;
          if (n < N) {
            size_t o = (size_t)(k0 + bkb * 4) * N + n;
            b0 = f2bf_bits(Bmat[o]);
            b1 = f2bf_bits(Bmat[o + (size_t)N]);
            b2 = f2bf_bits(Bmat[o + 2 * (size_t)N]);
            b3 = f2bf_bits(Bmat[o + 3 * (size_t)N]);
          }
          u32x2 w = {b0 | (b1 << 16), b2 | (b3 << 16)};
          *(u32x2*)&Bs[bnb * 4 + ii][bkb * 4] = w;
        }
      }
    }
    __syncthreads();

    short8 af[4], bfr[4];
#pragma unroll
    for (int t = 0; t < 4; ++t) {
      af[t]  = *(const short8*)&As[wm + t * 16 + fl][kg * 8];
      bfr[t] = *(const short8*)&Bs[wn + t * 16 + fl][kg * 8];
    }
#pragma unroll
    for (int tm = 0; tm < 4; ++tm)
#pragma unroll
      for (int tn = 0; tn < 4; ++tn)
        acc[tm][tn] = __builtin_amdgcn_mfma_f32_16x16x32_bf16(af[tm], bfr[tn], acc[tm][tn], 0, 0, 0);
    __syncthreads();
  }

#pragma unroll
  for (int tn = 0; tn < 4; ++tn) {
    int n = n0 + wn + tn * 16 + fl;
    if (n < N) {
      float bv = bias[n];
#pragma unroll
      for (int tm = 0; tm < 4; ++tm) {
        size_t base = (size_t)(m0 + wm + tm * 16 + kg * 4) * N + n;
#pragma unroll
        for (int r = 0; r < 4; ++r) {
          float v = acc[tm][tn][r] + bv;
          if constexpr (RELU) v = fmaxf(v, 0.f);
          if constexpr (OBF16)
            ((uint16_t*)Cp)[base + (size_t)r * N] = (uint16_t)f2bf_bits(v);
          else
            ((float*)Cp)[base + (size_t)r * N] = v;
        }
      }
    }
  }
}

extern "C" void kernel_launch(void* const* d_in, const int* in_sizes, int n_in,
                              void* d_out, int out_size, void* d_ws, size_t ws_size,
                              hipStream_t stream) {
  const float* X   = (const float*)d_in[0];
  const float* Win = (const float*)d_in[1];
  const float* bin = (const float*)d_in[2];
  const float* W1  = (const float*)d_in[3];
  const float* b1  = (const float*)d_in[4];
  const float* W2  = (const float*)d_in[5];
  const float* b2  = (const float*)d_in[6];
  float* out = (float*)d_out;

  const int Bm = 4096, DIN = 32000, H0 = 4000, H1 = 4000, TL = 2000;
  const size_t sX  = (size_t)Bm * DIN;
  const size_t sWi = (size_t)DIN * H0;
  const size_t sW1 = (size_t)H0 * H1;
  const size_t sW2 = (size_t)H1 * TL;
  const size_t st0 = (size_t)Bm * H0;
  const size_t st1 = (size_t)Bm * H1;
  const size_t need_fast = 2 * (sX + sWi + sW1 + sW2 + st0 + st1);  // ~602 MiB

  dim3 blk(256);

  if (ws_size >= need_fast) {
    // fast path: pre-convert X, pre-transpose+convert weights -> bf16
    uint8_t* w = (uint8_t*)d_ws;
    uint16_t* Xb  = (uint16_t*)w; w += 2 * sX;
    uint16_t* WiT = (uint16_t*)w; w += 2 * sWi;
    uint16_t* W1T = (uint16_t*)w; w += 2 * sW1;
    uint16_t* W2T = (uint16_t*)w; w += 2 * sW2;
    uint16_t* t0  = (uint16_t*)w; w += 2 * st0;
    uint16_t* t1  = (uint16_t*)w;

    cvt_bf16_kernel<<<dim3((unsigned)((sX / 8 + 255) / 256)), blk, 0, stream>>>(X, (uint32_t*)Xb, sX);
    cvtT_bf16_kernel<<<dim3((H0 + 31) / 32, DIN / 32), blk, 0, stream>>>(Win, WiT, DIN, H0);
    cvtT_bf16_kernel<<<dim3((H1 + 31) / 32, H0 / 32), blk, 0, stream>>>(W1, W1T, H0, H1);
    cvtT_bf16_kernel<<<dim3((TL + 31) / 32, H1 / 32), blk, 0, stream>>>(W2, W2T, H1, TL);

    mlp_gemm_fast<false, true><<<dim3((H0 + 127) / 128, Bm / 128), blk, 0, stream>>>(
        Xb, WiT, bin, t0, Bm, H0, DIN);
    mlp_gemm_fast<true, true><<<dim3((H1 + 127) / 128, Bm / 128), blk, 0, stream>>>(
        t0, W1T, b1, t1, Bm, H1, H0);
    mlp_gemm_fast<true, false><<<dim3((TL + 127) / 128, Bm / 128), blk, 0, stream>>>(
        t1, W2T, b2, out, Bm, TL, H1);
  } else {
    // slow path: inline conversion/transpose in GEMM staging; ws only for t0/t1
    uint16_t* t0 = (uint16_t*)d_ws;
    uint16_t* t1 = t0 + st0;

    mlp_gemm<false, false, false, true><<<dim3((H0 + 127) / 128, Bm / 128), blk, 0, stream>>>(
        X, Win, bin, t0, Bm, H0, DIN);
    mlp_gemm<true, false, true, true><<<dim3((H1 + 127) / 128, Bm / 128), blk, 0, stream>>>(
        t0, W1, b1, t1, Bm, H1, H0);
    mlp_gemm<true, false, true, false><<<dim3((TL + 127) / 128, Bm / 128), blk, 0, stream>>>(
        t1, W2, b2, out, Bm, TL, H1);
  }
}